// Round 3
// baseline (775.466 us; speedup 1.0000x reference)
//
#include <hip/hip_runtime.h>
#include <hip/hip_bf16.h>
#include <stdint.h>

#define BATCH  64
#define NFRAME 32
#define NBOX   36
#define REGION 1024
#define HIDDEN 1024
#define ATTSZ  1024
#define FEAT2  3072
#define M_S (BATCH * NFRAME * NBOX)   // 73728
#define M_T (BATCH * NFRAME)          // 2048

typedef __attribute__((ext_vector_type(8))) short bf16x8;
typedef __attribute__((ext_vector_type(4))) float f32x4;

__device__ __forceinline__ unsigned short f2bf(float f) {
  union { float f; uint32_t u; } v; v.f = f;
  return (unsigned short)((v.u + 0x7FFFu + ((v.u >> 16) & 1u)) >> 16);  // RNE
}
__device__ __forceinline__ float bf2f(unsigned short u) {
  union { uint32_t u; float f; } v; v.u = (uint32_t)u << 16; return v.f;
}
__device__ __forceinline__ float fast_tanh(float x) {
  float e = __expf(2.f * x);
  return 1.f - 2.f / (e + 1.f);
}
__device__ __forceinline__ void gload_lds16(const unsigned short* g, unsigned short* l) {
  __builtin_amdgcn_global_load_lds(
      (const __attribute__((address_space(1))) unsigned int*)g,
      (__attribute__((address_space(3))) unsigned int*)l, 16, 0, 0);
}
constexpr int clog2(int v) { return v <= 1 ? 0 : 1 + clog2(v >> 1); }

// ---------------------------------------------------------------------------
// Merged prep kernel: obj cast + score memset + weight casts.
// R3: grid-stride with 2048 blocks (G11) instead of 38986 one-shot blocks —
// ~19 independent iterations/thread for latency hiding. 453 MB streaming.
// Work item = 8 elems. Segments: [obj 9437184 | ms 9472 | wvs 131072 | wvt 393216].
// ---------------------------------------------------------------------------
__device__ __forceinline__ void cast8i(const float* __restrict__ in,
                                       unsigned short* __restrict__ out, long item) {
  long i = item * 8;
  float4 a = *(const float4*)(in + i);
  float4 b = *(const float4*)(in + i + 4);
  ushort4 lo; lo.x = f2bf(a.x); lo.y = f2bf(a.y); lo.z = f2bf(a.z); lo.w = f2bf(a.w);
  ushort4 hi; hi.x = f2bf(b.x); hi.y = f2bf(b.y); hi.z = f2bf(b.z); hi.w = f2bf(b.w);
  *(ushort4*)(out + i) = lo;
  *(ushort4*)(out + i + 4) = hi;
}

#define PREP_OBJ_ITEMS ((long)M_S * REGION / 8)       // 9437184
#define PREP_MS_ITEMS  ((M_S + M_T) / 8)              // 9472 (exact)
#define PREP_WVS_ITEMS ((long)ATTSZ * REGION / 8)     // 131072
#define PREP_WVT_ITEMS ((long)HIDDEN * FEAT2 / 8)     // 393216
#define PREP_TOTAL (PREP_OBJ_ITEMS + PREP_MS_ITEMS + PREP_WVS_ITEMS + PREP_WVT_ITEMS)
#define PREP_GRID 2048

__global__ __launch_bounds__(256) void prep(
    const float* __restrict__ obj, unsigned short* __restrict__ objb,
    const float* __restrict__ wvs, unsigned short* __restrict__ wvsb,
    const float* __restrict__ wvt, unsigned short* __restrict__ wvtb,
    float* __restrict__ score_zero)
{
  const long stride = (long)gridDim.x * 256;
  for (long it = (long)blockIdx.x * 256 + threadIdx.x; it < PREP_TOTAL; it += stride) {
    long i = it;
    if (i < PREP_OBJ_ITEMS) { cast8i(obj, objb, i); continue; }
    i -= PREP_OBJ_ITEMS;
    if (i < PREP_MS_ITEMS) {
      float4 z = {0.f, 0.f, 0.f, 0.f};
      *(float4*)(score_zero + i * 8)     = z;
      *(float4*)(score_zero + i * 8 + 4) = z;
      continue;
    }
    i -= PREP_MS_ITEMS;
    if (i < PREP_WVS_ITEMS) { cast8i(wvs, wvsb, i); continue; }
    i -= PREP_WVS_ITEMS;
    cast8i(wvt, wvtb, i);
  }
}

// ---------------------------------------------------------------------------
// Templated bf16 GEMM + tanh + row-score reduction.  (Proven: 800 TF on the
// spatial shape; m97-structure ceiling.  R1's 8-phase 256^2 rewrite regressed
// to 639 TF — do not re-attempt by description; the loop's own m232 also
// failed to reproduce 8-phase gains outside the exact m201 schedule.)
//   score[row] += sum_col tanh( (A @ W^T)[row][col] + h[b(row)][col] ) * wa[col]
// Block = 256 threads = 4 waves in 2x2; wave tile (TM*16) x (TN*16);
// block tile BM x BN, BK=64, global_load_lds staging.
// LDS XOR-swizzle: chunk = 8 rows x 8 granules(16B); slot (r,p) holds logical
// granule p^r -> conflict-free reads without padding (measured: 4.2e7 -> 0).
// LINGRID: bid%8 selects XCD; col-siblings placed 8 apart so a row-tile's A
// lives in ONE XCD L2 (measured: FETCH 305->107 MB).
// R3: rt_off arg allows splitting the M-range across multiple launches
// (visibility: 3 parts x ~64us expose hidden kernels in top-5 profiling).
// REQUIRES: BM-aligned row tiles within one batch.
// ---------------------------------------------------------------------------
template<int TM, int TN, bool LINGRID, int NCOLT>
__global__ __launch_bounds__(256, 3) void gemm_tanh_score(
    const unsigned short* __restrict__ A, const unsigned short* __restrict__ W,
    const float* __restrict__ hvec, const float* __restrict__ wa,
    float* __restrict__ score, int K, int rows_per_b, int rt_off)
{
  constexpr int BM = 2 * TM * 16;
  constexpr int BN = 2 * TN * 16;
  __shared__ __align__(16) unsigned short ldsA[BM * 64];
  __shared__ __align__(16) unsigned short ldsW[BN * 64];
  __shared__ float h_tile[BN];
  __shared__ float score_sh[2][BM];

  const int tid  = threadIdx.x;
  const int lane = tid & 63;
  const int wid  = tid >> 6;
  const int wr   = (wid >> 1) * (TM * 16);
  const int wc   = (wid & 1) * (TN * 16);
  const int l15  = lane & 15;
  const int q    = lane >> 4;
  const int rl   = l15 & 7;            // fragment-read swizzle key
  const int srow = lane >> 3;          // staging: row within 8-row chunk
  const int sgr  = (lane & 7) ^ srow;  // staging: swizzled source granule

  long r0; int c0;
  if (LINGRID) {
    int bid = blockIdx.x;
    int rt = (bid & 7) + (bid >> (3 + clog2(NCOLT))) * 8;
    int ct = (bid >> 3) & (NCOLT - 1);
    r0 = (long)(rt + rt_off) * BM; c0 = ct * BN;
  } else {
    r0 = (long)blockIdx.y * BM; c0 = blockIdx.x * BN;
  }
  const int b0 = (int)(r0 / rows_per_b);   // tile lies in one batch

  for (int i = tid; i < BN; i += 256)
    h_tile[i] = hvec[(long)b0 * ATTSZ + c0 + i];
  float wac[TN];
  #pragma unroll
  for (int j = 0; j < TN; ++j) wac[j] = wa[c0 + wc + j * 16 + l15];

  f32x4 acc[TM][TN] = {};

  for (int k0 = 0; k0 < K; k0 += 64) {
    __syncthreads();
    #pragma unroll
    for (int it = 0; it < BM / 32; ++it) {
      int c = wid * (BM / 32) + it;
      gload_lds16(A + (r0 + c * 8 + srow) * (long)K + k0 + (sgr << 3), ldsA + c * 512);
    }
    #pragma unroll
    for (int it = 0; it < BN / 32; ++it) {
      int c = wid * (BN / 32) + it;
      gload_lds16(W + ((long)(c0 + c * 8 + srow)) * K + k0 + (sgr << 3), ldsW + c * 512);
    }
    __syncthreads();
    #pragma unroll
    for (int s = 0; s < 2; ++s) {
      bf16x8 af[TM], wf[TN];
      const int gsw = ((s * 4 + q) ^ rl) << 3;    // swizzled granule offset
      #pragma unroll
      for (int i = 0; i < TM; ++i)
        af[i] = *(const bf16x8*)(ldsA + (wr + i * 16 + l15) * 64 + gsw);
      #pragma unroll
      for (int j = 0; j < TN; ++j)
        wf[j] = *(const bf16x8*)(ldsW + (wc + j * 16 + l15) * 64 + gsw);
      #pragma unroll
      for (int i = 0; i < TM; ++i)
        #pragma unroll
        for (int j = 0; j < TN; ++j)
          acc[i][j] = __builtin_amdgcn_mfma_f32_16x16x32_bf16(af[i], wf[j], acc[i][j], 0, 0, 0);
    }
  }

  // Epilogue: tanh(acc + h) * wa, quad-reduce over the 16 col-lanes.
  #pragma unroll
  for (int i = 0; i < TM; ++i) {
    #pragma unroll
    for (int r = 0; r < 4; ++r) {
      float part = 0.f;
      #pragma unroll
      for (int j = 0; j < TN; ++j) {
        float x = acc[i][j][r] + h_tile[wc + j * 16 + l15];
        part += fast_tanh(x) * wac[j];
      }
      part += __shfl_xor(part, 1); part += __shfl_xor(part, 2);
      part += __shfl_xor(part, 4); part += __shfl_xor(part, 8);
      if (l15 == 0) score_sh[wid & 1][wr + i * 16 + q * 4 + r] = part;
    }
  }
  __syncthreads();
  if (tid < BM)
    atomicAdd(score + r0 + tid, score_sh[0][tid] + score_sh[1][tid]);
}

// ---------------------------------------------------------------------------
// h projections (biases folded)
// ---------------------------------------------------------------------------
__global__ __launch_bounds__(256) void hidden_proj(
    const float* __restrict__ hidden,
    const float* __restrict__ s_wh_w, const float* __restrict__ s_wh_b,
    const float* __restrict__ s_wv_b,
    const float* __restrict__ t_wh_w, const float* __restrict__ t_wh_b,
    const float* __restrict__ t_wv_b,
    float* __restrict__ h_s, float* __restrict__ h_t)
{
  const float *W, *b1, *b2;
  float* out;
  if (blockIdx.y == 0) { W = s_wh_w; b1 = s_wh_b; b2 = s_wv_b; out = h_s; }
  else                 { W = t_wh_w; b1 = t_wh_b; b2 = t_wv_b; out = h_t; }
  const int lane = threadIdx.x & 63;
  const int wid  = threadIdx.x >> 6;
  const int a    = blockIdx.x * 4 + wid;
  __shared__ float hs[64 * 256];
  float acc[64];
  #pragma unroll
  for (int b = 0; b < 64; ++b) acc[b] = 0.f;

  for (int dc = 0; dc < 4; ++dc) {
    __syncthreads();
    for (int i = threadIdx.x; i < 4096; i += 256) {
      int b = i >> 6, d4 = i & 63;
      *(float4*)(hs + b * 256 + d4 * 4) =
          *(const float4*)(hidden + b * 1024 + dc * 256 + d4 * 4);
    }
    __syncthreads();
    float4 w4 = *(const float4*)(W + (long)a * 1024 + dc * 256 + lane * 4);
    #pragma unroll
    for (int b = 0; b < 64; ++b) {
      float4 h4 = *(const float4*)(hs + b * 256 + lane * 4);
      acc[b] += w4.x * h4.x + w4.y * h4.y + w4.z * h4.z + w4.w * h4.w;
    }
  }
  #pragma unroll
  for (int b = 0; b < 64; ++b) {
    #pragma unroll
    for (int off = 1; off < 64; off <<= 1)
      acc[b] += __shfl_xor(acc[b], off);
  }
  float res = 0.f;
  #pragma unroll
  for (int b = 0; b < 64; ++b)
    if (lane == b) res = acc[b];
  out[lane * 1024 + a] = res + b1[a] + b2[a];
}

// ---------------------------------------------------------------------------
// Spatial softmax + weighted sum (bf16 obj) -> feat fp32 + feat bf16
// ---------------------------------------------------------------------------
__global__ __launch_bounds__(256) void spatial_softmax_obj_bf16(
    const unsigned short* __restrict__ objb, const float* __restrict__ score,
    const float* __restrict__ frame, float* __restrict__ feat,
    unsigned short* __restrict__ featb)
{
  const int bf = blockIdx.x;
  __shared__ float alpha[NBOX];
  if (threadIdx.x < 64) {
    int n = threadIdx.x;
    float v = (n < NBOX) ? score[bf * NBOX + n] : -1e30f;
    float m = v;
    #pragma unroll
    for (int off = 32; off; off >>= 1) m = fmaxf(m, __shfl_xor(m, off));
    float e = (n < NBOX) ? __expf(v - m) : 0.f;
    float ssum = e;
    #pragma unroll
    for (int off = 32; off; off >>= 1) ssum += __shfl_xor(ssum, off);
    if (n < NBOX) alpha[n] = e / ssum;
  }
  __syncthreads();
  const unsigned short* base = objb + (long)bf * NBOX * REGION;
  float4 av = {0.f, 0.f, 0.f, 0.f};
  #pragma unroll 4
  for (int n = 0; n < NBOX; ++n) {
    float al = alpha[n];
    ushort4 o = *(const ushort4*)(base + n * REGION + threadIdx.x * 4);
    av.x += al * bf2f(o.x); av.y += al * bf2f(o.y);
    av.z += al * bf2f(o.z); av.w += al * bf2f(o.w);
  }
  float* frow = feat + (long)bf * FEAT2;
  unsigned short* fbrow = featb + (long)bf * FEAT2;
  *(float4*)(frow + threadIdx.x * 4) = av;
  ushort4 avb; avb.x = f2bf(av.x); avb.y = f2bf(av.y); avb.z = f2bf(av.z); avb.w = f2bf(av.w);
  *(ushort4*)(fbrow + threadIdx.x * 4) = avb;
  const float* fsrc = frame + (long)bf * 2 * HIDDEN;
  #pragma unroll
  for (int c = 0; c < 2; ++c) {
    float4 v = *(const float4*)(fsrc + (threadIdx.x + c * 256) * 4);
    *(float4*)(frow + REGION + (threadIdx.x + c * 256) * 4) = v;
    ushort4 vb; vb.x = f2bf(v.x); vb.y = f2bf(v.y); vb.z = f2bf(v.z); vb.w = f2bf(v.w);
    *(ushort4*)(fbrow + REGION + (threadIdx.x + c * 256) * 4) = vb;
  }
}

// ---------------------------------------------------------------------------
// Temporal softmax + weighted sum of fp32 feat -> out[B, 3072]
// grid (64, 3): blockIdx.y picks a 1024-col chunk.
// ---------------------------------------------------------------------------
__global__ __launch_bounds__(256) void temporal_out(
    const float* __restrict__ score2, const float* __restrict__ feat,
    float* __restrict__ out)
{
  const int b = blockIdx.x;
  __shared__ float beta[NFRAME];
  if (threadIdx.x < 64) {
    int f = threadIdx.x;
    float v = (f < NFRAME) ? score2[b * NFRAME + f] : -1e30f;
    float m = v;
    #pragma unroll
    for (int off = 32; off; off >>= 1) m = fmaxf(m, __shfl_xor(m, off));
    float e = (f < NFRAME) ? __expf(v - m) : 0.f;
    float ssum = e;
    #pragma unroll
    for (int off = 32; off; off >>= 1) ssum += __shfl_xor(ssum, off);
    if (f < NFRAME) beta[f] = e / ssum;
  }
  __syncthreads();
  int col = blockIdx.y * 1024 + threadIdx.x * 4;
  float4 av = {0.f, 0.f, 0.f, 0.f};
  #pragma unroll 4
  for (int f = 0; f < NFRAME; ++f) {
    float bw = beta[f];
    float4 v = *(const float4*)(feat + (long)(b * NFRAME + f) * FEAT2 + col);
    av.x += bw * v.x; av.y += bw * v.y; av.z += bw * v.z; av.w += bw * v.w;
  }
  *(float4*)(out + (long)b * FEAT2 + col) = av;
}

// ===========================================================================
// Fallback path (fp32 inputs, inline conversion) — only if ws too small.
// ===========================================================================
#define FBM 128
#define FBN 128
#define FBK 64
#define LDKP 72
__global__ __launch_bounds__(256) void fused_gemm_tanh_score_f32(
    const float* __restrict__ A, const float* __restrict__ W,
    const float* __restrict__ hvec, const float* __restrict__ wa,
    float* __restrict__ score, int M, int K, int rows_per_b)
{
  __shared__ unsigned short ldsA[FBM * LDKP];
  __shared__ unsigned short ldsW[FBN * LDKP];
  const int tid  = threadIdx.x;
  const int lane = tid & 63;
  const int wid  = tid >> 6;
  const int wr   = (wid >> 1) * 64;
  const int wc   = (wid & 1) * 64;
  const int l15  = lane & 15;
  const int q    = lane >> 4;
  const long r0  = (long)blockIdx.y * FBM;
  const int  c0  = blockIdx.x * FBN;

  f32x4 acc[4][4] = {};
  for (int k0 = 0; k0 < K; k0 += FBK) {
    __syncthreads();
    #pragma unroll
    for (int it = 0; it < 8; ++it) {
      int c = tid + it * 256;
      int row = c >> 4, qb = c & 15;
      float4 s = *(const float4*)(A + (r0 + row) * (long)K + k0 + qb * 4);
      ushort4 d; d.x = f2bf(s.x); d.y = f2bf(s.y); d.z = f2bf(s.z); d.w = f2bf(s.w);
      *(ushort4*)(ldsA + row * LDKP + qb * 4) = d;
    }
    #pragma unroll
    for (int it = 0; it < 8; ++it) {
      int c = tid + it * 256;
      int row = c >> 4, qb = c & 15;
      float4 s = *(const float4*)(W + (c0 + row) * (long)K + k0 + qb * 4);
      ushort4 d; d.x = f2bf(s.x); d.y = f2bf(s.y); d.z = f2bf(s.z); d.w = f2bf(s.w);
      *(ushort4*)(ldsW + row * LDKP + qb * 4) = d;
    }
    __syncthreads();
    #pragma unroll
    for (int s = 0; s < 2; ++s) {
      bf16x8 af[4], bfr[4];
      #pragma unroll
      for (int i = 0; i < 4; ++i)
        af[i] = *(const bf16x8*)(ldsA + (wr + i * 16 + l15) * LDKP + s * 32 + q * 8);
      #pragma unroll
      for (int j = 0; j < 4; ++j)
        bfr[j] = *(const bf16x8*)(ldsW + (wc + j * 16 + l15) * LDKP + s * 32 + q * 8);
      #pragma unroll
      for (int i = 0; i < 4; ++i)
        #pragma unroll
        for (int j = 0; j < 4; ++j)
          acc[i][j] = __builtin_amdgcn_mfma_f32_16x16x32_bf16(af[i], bfr[j], acc[i][j], 0, 0, 0);
    }
  }
  float wac[4];
  #pragma unroll
  for (int j = 0; j < 4; ++j) wac[j] = wa[c0 + wc + j * 16 + l15];
  #pragma unroll
  for (int i = 0; i < 4; ++i) {
    #pragma unroll
    for (int r = 0; r < 4; ++r) {
      int row = (int)r0 + wr + i * 16 + q * 4 + r;
      const float* hrow = hvec + (long)(row / rows_per_b) * ATTSZ;
      float part = 0.f;
      #pragma unroll
      for (int j = 0; j < 4; ++j) {
        float x = acc[i][j][r] + hrow[c0 + wc + j * 16 + l15];
        part += fast_tanh(x) * wac[j];
      }
      part += __shfl_xor(part, 1); part += __shfl_xor(part, 2);
      part += __shfl_xor(part, 4); part += __shfl_xor(part, 8);
      if (l15 == 0) atomicAdd(score + row, part);
    }
  }
}

__global__ __launch_bounds__(256) void spatial_softmax_obj_f32(
    const float* __restrict__ obj, const float* __restrict__ score,
    const float* __restrict__ frame, float* __restrict__ feat)
{
  const int bf = blockIdx.x;
  __shared__ float alpha[NBOX];
  if (threadIdx.x < 64) {
    int n = threadIdx.x;
    float v = (n < NBOX) ? score[bf * NBOX + n] : -1e30f;
    float m = v;
    #pragma unroll
    for (int off = 32; off; off >>= 1) m = fmaxf(m, __shfl_xor(m, off));
    float e = (n < NBOX) ? __expf(v - m) : 0.f;
    float ssum = e;
    #pragma unroll
    for (int off = 32; off; off >>= 1) ssum += __shfl_xor(ssum, off);
    if (n < NBOX) alpha[n] = e / ssum;
  }
  __syncthreads();
  const float* base = obj + (long)bf * NBOX * REGION;
  float4 av = {0.f, 0.f, 0.f, 0.f};
  for (int n = 0; n < NBOX; ++n) {
    float al = alpha[n];
    float4 o = *(const float4*)(base + n * REGION + threadIdx.x * 4);
    av.x += al * o.x; av.y += al * o.y; av.z += al * o.z; av.w += al * o.w;
  }
  float* frow = feat + (long)bf * FEAT2;
  *(float4*)(frow + threadIdx.x * 4) = av;
  const float4* fsrc = (const float4*)(frame + (long)bf * 2 * HIDDEN);
  float4* fdst = (float4*)(frow + REGION);
  fdst[threadIdx.x]       = fsrc[threadIdx.x];
  fdst[threadIdx.x + 256] = fsrc[threadIdx.x + 256];
}

__global__ __launch_bounds__(256) void temporal_out_f32(
    const float* __restrict__ score2, const float* __restrict__ feat,
    float* __restrict__ out)
{
  const int b = blockIdx.x;
  __shared__ float beta[NFRAME];
  if (threadIdx.x < 64) {
    int f = threadIdx.x;
    float v = (f < NFRAME) ? score2[b * NFRAME + f] : -1e30f;
    float m = v;
    #pragma unroll
    for (int off = 32; off; off >>= 1) m = fmaxf(m, __shfl_xor(m, off));
    float e = (f < NFRAME) ? __expf(v - m) : 0.f;
    float ssum = e;
    #pragma unroll
    for (int off = 32; off; off >>= 1) ssum += __shfl_xor(ssum, off);
    if (f < NFRAME) beta[f] = e / ssum;
  }
  __syncthreads();
  #pragma unroll
  for (int c = 0; c < 3; ++c) {
    int col = (threadIdx.x + c * 256) * 4;
    float4 av = {0.f, 0.f, 0.f, 0.f};
    for (int f = 0; f < NFRAME; ++f) {
      float bw = beta[f];
      float4 v = *(const float4*)(feat + (long)(b * NFRAME + f) * FEAT2 + col);
      av.x += bw * v.x; av.y += bw * v.y; av.z += bw * v.z; av.w += bw * v.w;
    }
    *(float4*)(out + (long)b * FEAT2 + col) = av;
  }
}

// ---------------------------------------------------------------------------
extern "C" void kernel_launch(void* const* d_in, const int* in_sizes, int n_in,
                              void* d_out, int out_size, void* d_ws, size_t ws_size,
                              hipStream_t stream) {
  const float* frame  = (const float*)d_in[0];
  const float* obj    = (const float*)d_in[1];
  const float* hidden = (const float*)d_in[2];
  const float* s_wh_w = (const float*)d_in[3];
  const float* s_wh_b = (const float*)d_in[4];
  const float* s_wv_w = (const float*)d_in[5];
  const float* s_wv_b = (const float*)d_in[6];
  const float* s_wa_w = (const float*)d_in[7];
  const float* t_wh_w = (const float*)d_in[8];
  const float* t_wh_b = (const float*)d_in[9];
  const float* t_wv_w = (const float*)d_in[10];
  const float* t_wv_b = (const float*)d_in[11];
  const float* t_wa_w = (const float*)d_in[12];
  float* out = (float*)d_out;

  char* p = (char*)d_ws;
  auto alloc = [&](size_t bytes) { char* r = p; p += (bytes + 255) & ~255ull; return r; };
  float* h_s     = (float*)alloc(65536 * 4);
  float* h_t     = (float*)alloc(65536 * 4);
  float* score_s = (float*)alloc((size_t)M_S * 4);   // contiguous with score2
  float* score2  = (float*)alloc((size_t)M_T * 4);
  float* feat    = (float*)alloc((size_t)M_T * FEAT2 * 4);
  unsigned short* objb  = (unsigned short*)alloc((size_t)M_S * REGION * 2);
  unsigned short* featb = (unsigned short*)alloc((size_t)M_T * FEAT2 * 2);
  unsigned short* wvsb  = (unsigned short*)alloc((size_t)ATTSZ * REGION * 2);
  unsigned short* wvtb  = (unsigned short*)alloc((size_t)HIDDEN * FEAT2 * 2);
  size_t needed = (size_t)(p - (char*)d_ws);
  bool fast = needed <= ws_size;

  if (fast) {
    prep<<<PREP_GRID, 256, 0, stream>>>(obj, objb, s_wv_w, wvsb, t_wv_w, wvtb, score_s);

    hidden_proj<<<dim3(256, 2), 256, 0, stream>>>(
        hidden, s_wh_w, s_wh_b, s_wv_b, t_wh_w, t_wh_b, t_wv_b, h_s, h_t);

    // Spatial: 128x128 tiles, split into 3 equal M-ranges (192 row-tiles
    // each = 1536 blocks = exactly 2 residency rounds at 3 blocks/CU).
    // Same math/atomics as the single launch; split is for profiling
    // visibility (each part ~64us -> hidden kernels >64us surface in top-5).
    gemm_tanh_score<4, 4, true, 8><<<dim3(1536), 256, 0, stream>>>(
        objb, wvsb, h_s, s_wa_w, score_s, REGION, NFRAME * NBOX, 0);
    gemm_tanh_score<4, 4, true, 8><<<dim3(1536), 256, 0, stream>>>(
        objb, wvsb, h_s, s_wa_w, score_s, REGION, NFRAME * NBOX, 192);
    gemm_tanh_score<4, 4, true, 8><<<dim3(1536), 256, 0, stream>>>(
        objb, wvsb, h_s, s_wa_w, score_s, REGION, NFRAME * NBOX, 384);

    spatial_softmax_obj_bf16<<<M_T, 256, 0, stream>>>(objb, score_s, frame, feat, featb);

    // Temporal: 32x128 tiles, grid (8, 64) = 512 blocks.
    gemm_tanh_score<1, 4, false, 8><<<dim3(8, M_T / 32), 256, 0, stream>>>(
        featb, wvtb, h_t, t_wa_w, score2, FEAT2, NFRAME, 0);

    temporal_out<<<dim3(BATCH, 3), 256, 0, stream>>>(score2, feat, out);
  } else {
    hipMemsetAsync(score_s, 0, (size_t)(M_S + M_T) * sizeof(float), stream);
    hidden_proj<<<dim3(256, 2), 256, 0, stream>>>(
        hidden, s_wh_w, s_wh_b, s_wv_b, t_wh_w, t_wh_b, t_wv_b, h_s, h_t);
    fused_gemm_tanh_score_f32<<<dim3(8, M_S / FBM), 256, 0, stream>>>(
        obj, s_wv_w, h_s, s_wa_w, score_s, M_S, REGION, NFRAME * NBOX);
    spatial_softmax_obj_f32<<<M_T, 256, 0, stream>>>(obj, score_s, frame, feat);
    fused_gemm_tanh_score_f32<<<dim3(8, M_T / FBM), 256, 0, stream>>>(
        feat, t_wv_w, h_t, t_wa_w, score2, M_T, FEAT2, NFRAME);
    temporal_out_f32<<<BATCH, 256, 0, stream>>>(score2, feat, out);
  }
}